// Round 2
// baseline (6234.733 us; speedup 1.0000x reference)
//
#include <hip/hip_runtime.h>
#include <cstdint>
#include <cstddef>

#define NN 50000
#define NE 800000
#define NG 64
#define IND 768
#define HID 256
#define NREL 3
#define NLAY 3

// ---------------- utility ----------------
__global__ void k_zero_int(int* __restrict__ p, int n) {
  int i = blockIdx.x * 256 + threadIdx.x;
  if (i < n) p[i] = 0;
}

__global__ void k_hist(const int* __restrict__ dst, int* __restrict__ deg) {
  int e = blockIdx.x * 256 + threadIdx.x;
  if (e < NE) atomicAdd(&deg[dst[e]], 1);
}

// single-block scan over padded deg (53248 ints) -> row_start[NN+1], cursor[NN]
__global__ __launch_bounds__(1024) void k_scan(const int* __restrict__ deg,
                                               int* __restrict__ row_start,
                                               int* __restrict__ cursor) {
  __shared__ int wsum[16];
  int t = threadIdx.x;
  int lane = t & 63, wid = t >> 6;
  int running = 0;
  if (t == 0) row_start[0] = 0;
  for (int base = 0; base < NN; base += 4096) {
    int idx = base + t * 4;
    int4 d = *(const int4*)(deg + idx);  // deg padded+zeroed to 53248
    int s = d.x + d.y + d.z + d.w;
    int sc = s;
    #pragma unroll
    for (int off = 1; off < 64; off <<= 1) {
      int o = __shfl_up(sc, off);
      if (lane >= off) sc += o;
    }
    if (lane == 63) wsum[wid] = sc;
    __syncthreads();
    if (t == 0) {
      int a = 0;
      #pragma unroll
      for (int i = 0; i < 16; ++i) { a += wsum[i]; wsum[i] = a; }
    }
    __syncthreads();
    int woff = (wid == 0) ? 0 : wsum[wid - 1];
    int excl = running + woff + (sc - s);
    int e0 = excl, e1 = e0 + d.x, e2 = e1 + d.y, e3 = e2 + d.z, e4 = e3 + d.w;
    if (idx     < NN) { cursor[idx]     = e0; row_start[idx + 1] = e1; }
    if (idx + 1 < NN) { cursor[idx + 1] = e1; row_start[idx + 2] = e2; }
    if (idx + 2 < NN) { cursor[idx + 2] = e2; row_start[idx + 3] = e3; }
    if (idx + 3 < NN) { cursor[idx + 3] = e3; row_start[idx + 4] = e4; }
    running += wsum[15];
    __syncthreads();
  }
}

__global__ void k_scatter(const int* __restrict__ src, const int* __restrict__ dst,
                          const int* __restrict__ ety, int* __restrict__ cursor,
                          unsigned* __restrict__ csr) {
  int e = blockIdx.x * 256 + threadIdx.x;
  if (e >= NE) return;
  int pos = atomicAdd(&cursor[dst[e]], 1);
  csr[pos] = (unsigned)src[e] | ((unsigned)ety[e] << 16);  // src < 65536 fits 16 bits
}

__global__ void k_graph_bounds(const int* __restrict__ batch, int* __restrict__ gstart) {
  int i = blockIdx.x * 256 + threadIdx.x;
  if (i >= NN) return;
  int b = batch[i];
  int bp = (i == 0) ? -1 : batch[i - 1];
  for (int g = bp + 1; g <= b; ++g) gstart[g] = i;
  if (i == NN - 1) {
    for (int g = b + 1; g <= NG; ++g) gstart[g] = NN;
  }
}

// ---------------- aggregation: per-node mean per relation ----------------
// one 64-thread block per node; thread t owns channels [4t, 4t+4)
__global__ __launch_bounds__(64) void k_aggregate(const float* __restrict__ h,
                                                  const int* __restrict__ row_start,
                                                  const unsigned* __restrict__ csr,
                                                  float* __restrict__ agg) {
  int n = blockIdx.x;
  int t = threadIdx.x;
  int s = row_start[n], e = row_start[n + 1];
  float4 a0 = {0, 0, 0, 0}, a1 = {0, 0, 0, 0}, a2 = {0, 0, 0, 0};
  int c0 = 0, c1 = 0, c2 = 0;
  __shared__ unsigned buf[64];
  for (int base = s; base < e; base += 64) {
    int m = e - base; if (m > 64) m = 64;
    __syncthreads();
    if (t < m) buf[t] = csr[base + t];
    __syncthreads();
    for (int j = 0; j < m; ++j) {
      unsigned p = buf[j];
      int src = p & 0xFFFF;
      int ty = (int)(p >> 16);   // wave-uniform
      float4 v = *(const float4*)(h + (size_t)src * HID + t * 4);
      if (ty == 0)      { a0.x += v.x; a0.y += v.y; a0.z += v.z; a0.w += v.w; c0++; }
      else if (ty == 1) { a1.x += v.x; a1.y += v.y; a1.z += v.z; a1.w += v.w; c1++; }
      else              { a2.x += v.x; a2.y += v.y; a2.z += v.z; a2.w += v.w; c2++; }
    }
  }
  float i0 = 1.f / (float)(c0 > 1 ? c0 : 1);
  float i1 = 1.f / (float)(c1 > 1 ? c1 : 1);
  float i2 = 1.f / (float)(c2 > 1 ? c2 : 1);
  float* o = agg + (size_t)n * (NREL * HID) + t * 4;
  float4 r0 = {a0.x * i0, a0.y * i0, a0.z * i0, a0.w * i0};
  float4 r1 = {a1.x * i1, a1.y * i1, a1.z * i1, a1.w * i1};
  float4 r2 = {a2.x * i2, a2.y * i2, a2.z * i2, a2.w * i2};
  *(float4*)(o)           = r0;
  *(float4*)(o + HID)     = r1;
  *(float4*)(o + 2 * HID) = r2;
}

// ---------------- fused GEMM ----------------
// C[M][256] = [A1 | A2] @ [B1 ; B2] + bias, optionally + residual, ReLU, LayerNorm
// BM=64 BN=256 BK=32, 256 threads, thread tile 8 rows x (4+4) cols.
// Column tile split as [colg*4, +4) u [colg*4+128, +4): B-read lane stride 16B
// -> 4-way LDS bank conflict (1.58x) instead of 8-way (2.94x) with 8-wide tiles.
// Register-prefetch of tile k+1 before compute of tile k hides global latency.
#define BM 64
#define BN 256
#define BK 32

template <int EPI>  // 0 = bias only, 1 = bias + residual + relu + layernorm
__global__ __launch_bounds__(256, 4) void k_gemm(
    const float* __restrict__ A1, int lda1,
    const float* __restrict__ A2, int lda2, int K1,
    const float* __restrict__ B1, const float* __restrict__ B2,
    const float* __restrict__ bias, const float* __restrict__ res,
    const float* __restrict__ lnw, const float* __restrict__ lnb,
    float* __restrict__ C, int M, int K) {
  __shared__ float As[BK][BM];   // transposed: As[k][r]
  __shared__ float Bs[BK][BN];
  int tid = (int)threadIdx.x;
  int n0 = (int)blockIdx.x * BM;
  int rowg = tid >> 5, colg = tid & 31;
  int r0 = rowg * 8;
  int c0 = colg * 4;             // owns cols [c0,c0+4) and [c0+128,c0+132)
  float acc[8][8] = {};

  int rr = tid >> 3;             // 0..31
  int k4 = (tid & 7) << 2;       // 0,4,...,28

  float4 av[2];
  float4 bv[8];
  auto load_tile = [&](int kk) {
    const float* Ap; int ldA; int kcol;
    if (kk < K1) { Ap = A1; ldA = lda1; kcol = kk; }
    else         { Ap = A2; ldA = lda2; kcol = kk - K1; }
    #pragma unroll
    for (int hh = 0; hh < 2; ++hh) {
      int grow = n0 + rr + hh * 32;
      if (grow > M - 1) grow = M - 1;
      av[hh] = *(const float4*)(Ap + (size_t)grow * ldA + kcol + k4);
    }
    const float* Bp = (kk < K1) ? (B1 + (size_t)kk * BN) : (B2 + (size_t)(kk - K1) * BN);
    #pragma unroll
    for (int rnd = 0; rnd < 8; ++rnd) {
      int f = rnd * 256 + tid;
      bv[rnd] = *(const float4*)(Bp + (f >> 6) * BN + ((f & 63) << 2));
    }
  };

  load_tile(0);
  for (int kk = 0; kk < K; kk += BK) {
    __syncthreads();   // protect LDS from previous iteration's readers
    #pragma unroll
    for (int hh = 0; hh < 2; ++hh) {
      int r = rr + hh * 32;
      As[k4 + 0][r] = av[hh].x; As[k4 + 1][r] = av[hh].y;
      As[k4 + 2][r] = av[hh].z; As[k4 + 3][r] = av[hh].w;
    }
    #pragma unroll
    for (int rnd = 0; rnd < 8; ++rnd) {
      int f = rnd * 256 + tid;
      *(float4*)&Bs[f >> 6][(f & 63) << 2] = bv[rnd];
    }
    __syncthreads();
    if (kk + BK < K) load_tile(kk + BK);   // prefetch next tile into regs
    #pragma unroll
    for (int k = 0; k < BK; ++k) {
      float a[8], b[8];
      *(float4*)&a[0] = *(const float4*)&As[k][r0];
      *(float4*)&a[4] = *(const float4*)&As[k][r0 + 4];
      *(float4*)&b[0] = *(const float4*)&Bs[k][c0];
      *(float4*)&b[4] = *(const float4*)&Bs[k][c0 + 128];
      #pragma unroll
      for (int i = 0; i < 8; ++i)
        #pragma unroll
        for (int j = 0; j < 8; ++j)
          acc[i][j] = fmaf(a[i], b[j], acc[i][j]);
    }
  }

  // epilogue — thread's cols: j<4 -> c0+j ; j>=4 -> c0+128+(j-4)
  float bw[8];
  *(float4*)&bw[0] = *(const float4*)(bias + c0);
  *(float4*)&bw[4] = *(const float4*)(bias + c0 + 128);
  float lw[8], lB[8];
  if (EPI == 1) {
    *(float4*)&lw[0] = *(const float4*)(lnw + c0);
    *(float4*)&lw[4] = *(const float4*)(lnw + c0 + 128);
    *(float4*)&lB[0] = *(const float4*)(lnb + c0);
    *(float4*)&lB[4] = *(const float4*)(lnb + c0 + 128);
  }
  #pragma unroll
  for (int i = 0; i < 8; ++i) {
    int row = n0 + r0 + i;
    if (EPI == 0) {
      if (row < M) {
        float4 o0 = {acc[i][0] + bw[0], acc[i][1] + bw[1], acc[i][2] + bw[2], acc[i][3] + bw[3]};
        float4 o1 = {acc[i][4] + bw[4], acc[i][5] + bw[5], acc[i][6] + bw[6], acc[i][7] + bw[7]};
        *(float4*)(C + (size_t)row * BN + c0)       = o0;
        *(float4*)(C + (size_t)row * BN + c0 + 128) = o1;
      }
    } else {
      int rc = row < M ? row : M - 1;
      float4 rv0 = *(const float4*)(res + (size_t)rc * BN + c0);
      float4 rv1 = *(const float4*)(res + (size_t)rc * BN + c0 + 128);
      float v[8];
      v[0] = fmaxf(acc[i][0] + bw[0] + rv0.x, 0.f);
      v[1] = fmaxf(acc[i][1] + bw[1] + rv0.y, 0.f);
      v[2] = fmaxf(acc[i][2] + bw[2] + rv0.z, 0.f);
      v[3] = fmaxf(acc[i][3] + bw[3] + rv0.w, 0.f);
      v[4] = fmaxf(acc[i][4] + bw[4] + rv1.x, 0.f);
      v[5] = fmaxf(acc[i][5] + bw[5] + rv1.y, 0.f);
      v[6] = fmaxf(acc[i][6] + bw[6] + rv1.z, 0.f);
      v[7] = fmaxf(acc[i][7] + bw[7] + rv1.w, 0.f);
      float s = 0.f, s2 = 0.f;
      #pragma unroll
      for (int j = 0; j < 8; ++j) { s += v[j]; s2 += v[j] * v[j]; }
      #pragma unroll
      for (int mm = 1; mm < 32; mm <<= 1) {
        s  += __shfl_xor(s, mm);
        s2 += __shfl_xor(s2, mm);
      }
      float mean = s * (1.f / 256.f);
      float var = s2 * (1.f / 256.f) - mean * mean;
      float rstd = rsqrtf(var + 1e-5f);
      if (row < M) {
        float4 o0 = {(v[0] - mean) * rstd * lw[0] + lB[0], (v[1] - mean) * rstd * lw[1] + lB[1],
                     (v[2] - mean) * rstd * lw[2] + lB[2], (v[3] - mean) * rstd * lw[3] + lB[3]};
        float4 o1 = {(v[4] - mean) * rstd * lw[4] + lB[4], (v[5] - mean) * rstd * lw[5] + lB[5],
                     (v[6] - mean) * rstd * lw[6] + lB[6], (v[7] - mean) * rstd * lw[7] + lB[7]};
        *(float4*)(C + (size_t)row * BN + c0)       = o0;
        *(float4*)(C + (size_t)row * BN + c0 + 128) = o1;
      }
    }
  }
}

// ---------------- pooling + classifier ----------------
__global__ void k_pool(const float* __restrict__ h, const int* __restrict__ gstart,
                       float* __restrict__ g) {
  int gi = blockIdx.x;
  int c = blockIdx.y * 128 + threadIdx.x;
  int s = gstart[gi], e = gstart[gi + 1];
  float m = -3.402823466e+38f;
  for (int n = s; n < e; ++n) m = fmaxf(m, h[(size_t)n * HID + c]);
  g[gi * HID + c] = m;
}

__global__ __launch_bounds__(256) void k_classifier(const float* __restrict__ g,
                                                    const float* __restrict__ w1,
                                                    const float* __restrict__ b1,
                                                    const float* __restrict__ w2,
                                                    const float* __restrict__ b2,
                                                    float* __restrict__ out) {
  int gi = blockIdx.x, t = (int)threadIdx.x;
  __shared__ float gs[HID], zs[HID];
  gs[t] = g[gi * HID + t];
  __syncthreads();
  float s = b1[t];
  for (int k = 0; k < HID; ++k) s = fmaf(gs[k], w1[k * HID + t], s);
  zs[t] = fmaxf(s, 0.f);
  __syncthreads();
  if (t < 4) {
    float o = b2[t];
    for (int k = 0; k < HID; ++k) o = fmaf(zs[k], w2[k * 4 + t], o);
    out[gi * 4 + t] = o;
  }
}

// ---------------- launch ----------------
extern "C" void kernel_launch(void* const* d_in, const int* in_sizes, int n_in,
                              void* d_out, int out_size, void* d_ws, size_t ws_size,
                              hipStream_t stream) {
  const float* x      = (const float*)d_in[0];
  const int*   eidx   = (const int*)d_in[1];
  const int*   etype  = (const int*)d_in[2];
  const int*   batch  = (const int*)d_in[3];
  const float* in_w   = (const float*)d_in[4];
  const float* in_b   = (const float*)d_in[5];
  const float* root_w = (const float*)d_in[6];
  const float* rel_w  = (const float*)d_in[7];
  const float* conv_b = (const float*)d_in[8];
  const float* ln_w   = (const float*)d_in[9];
  const float* ln_b   = (const float*)d_in[10];
  const float* cls_w1 = (const float*)d_in[11];
  const float* cls_b1 = (const float*)d_in[12];
  const float* cls_w2 = (const float*)d_in[13];
  const float* cls_b2 = (const float*)d_in[14];
  float* out = (float*)d_out;

  char* ws = (char*)d_ws;
  size_t off = 0;
  auto alloc = [&](size_t bytes) -> void* {
    void* p = ws + off;
    off += (bytes + 255) & ~(size_t)255;
    return p;
  };
  float*    bufA      = (float*)alloc(sizeof(float) * (size_t)NN * HID);
  float*    bufB      = (float*)alloc(sizeof(float) * (size_t)NN * HID);
  float*    agg       = (float*)alloc(sizeof(float) * (size_t)NN * NREL * HID);
  unsigned* csr       = (unsigned*)alloc(sizeof(unsigned) * NE);
  int*      deg       = (int*)alloc(sizeof(int) * 53248);
  int*      row_start = (int*)alloc(sizeof(int) * (NN + 1));
  int*      cursor    = (int*)alloc(sizeof(int) * NN);
  int*      gstart    = (int*)alloc(sizeof(int) * (NG + 1));
  float*    gpool     = (float*)alloc(sizeof(float) * NG * HID);
  (void)ws_size; (void)in_sizes; (void)n_in; (void)out_size;

  const int* esrc = eidx;
  const int* edst = eidx + NE;

  k_zero_int<<<(53248 + 255) / 256, 256, 0, stream>>>(deg, 53248);
  k_hist<<<(NE + 255) / 256, 256, 0, stream>>>(edst, deg);
  k_scan<<<1, 1024, 0, stream>>>(deg, row_start, cursor);
  k_scatter<<<(NE + 255) / 256, 256, 0, stream>>>(esrc, edst, etype, cursor, csr);
  k_graph_bounds<<<(NN + 255) / 256, 256, 0, stream>>>(batch, gstart);

  int gemm_grid = (NN + BM - 1) / BM;
  // input projection: h = x @ in_w + in_b
  k_gemm<0><<<gemm_grid, 256, 0, stream>>>(x, IND, nullptr, 0, IND,
                                           in_w, nullptr, in_b, nullptr, nullptr, nullptr,
                                           bufA, NN, IND);

  float* hcur = bufA;
  float* hnext = bufB;
  for (int L = 0; L < NLAY; ++L) {
    k_aggregate<<<NN, 64, 0, stream>>>(hcur, row_start, csr, agg);
    k_gemm<1><<<gemm_grid, 256, 0, stream>>>(
        hcur, HID, agg, NREL * HID, HID,
        root_w + (size_t)L * HID * HID, rel_w + (size_t)L * NREL * HID * HID,
        conv_b + L * HID, hcur, ln_w + L * HID, ln_b + L * HID,
        hnext, NN, HID + NREL * HID);
    float* tmp = hcur; hcur = hnext; hnext = tmp;
  }

  k_pool<<<dim3(NG, 2), 128, 0, stream>>>(hcur, gstart, gpool);
  k_classifier<<<NG, 256, 0, stream>>>(gpool, cls_w1, cls_b1, cls_w2, cls_b2, out);
}

// Round 3
// 2646.610 us; speedup vs baseline: 2.3557x; 2.3557x over previous
//
#include <hip/hip_runtime.h>
#include <cstdint>
#include <cstddef>

#define NN 50000
#define NE 800000
#define NG 64
#define IND 768
#define HID 256
#define NREL 3
#define NLAY 3

// ---------------- utility ----------------
__global__ void k_zero_int(int* __restrict__ p, int n) {
  int i = blockIdx.x * 256 + threadIdx.x;
  if (i < n) p[i] = 0;
}

__global__ void k_hist(const int* __restrict__ dst, int* __restrict__ deg) {
  int e = blockIdx.x * 256 + threadIdx.x;
  if (e < NE) atomicAdd(&deg[dst[e]], 1);
}

// single-block scan over padded deg (53248 ints) -> row_start[NN+1], cursor[NN]
__global__ __launch_bounds__(1024) void k_scan(const int* __restrict__ deg,
                                               int* __restrict__ row_start,
                                               int* __restrict__ cursor) {
  __shared__ int wsum[16];
  int t = threadIdx.x;
  int lane = t & 63, wid = t >> 6;
  int running = 0;
  if (t == 0) row_start[0] = 0;
  for (int base = 0; base < NN; base += 4096) {
    int idx = base + t * 4;
    int4 d = *(const int4*)(deg + idx);  // deg padded+zeroed to 53248
    int s = d.x + d.y + d.z + d.w;
    int sc = s;
    #pragma unroll
    for (int off = 1; off < 64; off <<= 1) {
      int o = __shfl_up(sc, off);
      if (lane >= off) sc += o;
    }
    if (lane == 63) wsum[wid] = sc;
    __syncthreads();
    if (t == 0) {
      int a = 0;
      #pragma unroll
      for (int i = 0; i < 16; ++i) { a += wsum[i]; wsum[i] = a; }
    }
    __syncthreads();
    int woff = (wid == 0) ? 0 : wsum[wid - 1];
    int excl = running + woff + (sc - s);
    int e0 = excl, e1 = e0 + d.x, e2 = e1 + d.y, e3 = e2 + d.z, e4 = e3 + d.w;
    if (idx     < NN) { cursor[idx]     = e0; row_start[idx + 1] = e1; }
    if (idx + 1 < NN) { cursor[idx + 1] = e1; row_start[idx + 2] = e2; }
    if (idx + 2 < NN) { cursor[idx + 2] = e2; row_start[idx + 3] = e3; }
    if (idx + 3 < NN) { cursor[idx + 3] = e3; row_start[idx + 4] = e4; }
    running += wsum[15];
    __syncthreads();
  }
}

__global__ void k_scatter(const int* __restrict__ src, const int* __restrict__ dst,
                          const int* __restrict__ ety, int* __restrict__ cursor,
                          unsigned* __restrict__ csr) {
  int e = blockIdx.x * 256 + threadIdx.x;
  if (e >= NE) return;
  int pos = atomicAdd(&cursor[dst[e]], 1);
  csr[pos] = (unsigned)src[e] | ((unsigned)ety[e] << 16);  // src < 65536 fits 16 bits
}

__global__ void k_graph_bounds(const int* __restrict__ batch, int* __restrict__ gstart) {
  int i = blockIdx.x * 256 + threadIdx.x;
  if (i >= NN) return;
  int b = batch[i];
  int bp = (i == 0) ? -1 : batch[i - 1];
  for (int g = bp + 1; g <= b; ++g) gstart[g] = i;
  if (i == NN - 1) {
    for (int g = b + 1; g <= NG; ++g) gstart[g] = NN;
  }
}

// ---------------- aggregation: per-node mean per relation ----------------
// one 64-thread block per node; thread t owns channels [4t, 4t+4)
__global__ __launch_bounds__(64) void k_aggregate(const float* __restrict__ h,
                                                  const int* __restrict__ row_start,
                                                  const unsigned* __restrict__ csr,
                                                  float* __restrict__ agg) {
  int n = blockIdx.x;
  int t = threadIdx.x;
  int s = row_start[n], e = row_start[n + 1];
  float4 a0 = {0, 0, 0, 0}, a1 = {0, 0, 0, 0}, a2 = {0, 0, 0, 0};
  int c0 = 0, c1 = 0, c2 = 0;
  __shared__ unsigned buf[64];
  for (int base = s; base < e; base += 64) {
    int m = e - base; if (m > 64) m = 64;
    __syncthreads();
    if (t < m) buf[t] = csr[base + t];
    __syncthreads();
    for (int j = 0; j < m; ++j) {
      unsigned p = buf[j];
      int src = p & 0xFFFF;
      int ty = (int)(p >> 16);   // wave-uniform
      float4 v = *(const float4*)(h + (size_t)src * HID + t * 4);
      if (ty == 0)      { a0.x += v.x; a0.y += v.y; a0.z += v.z; a0.w += v.w; c0++; }
      else if (ty == 1) { a1.x += v.x; a1.y += v.y; a1.z += v.z; a1.w += v.w; c1++; }
      else              { a2.x += v.x; a2.y += v.y; a2.z += v.z; a2.w += v.w; c2++; }
    }
  }
  float i0 = 1.f / (float)(c0 > 1 ? c0 : 1);
  float i1 = 1.f / (float)(c1 > 1 ? c1 : 1);
  float i2 = 1.f / (float)(c2 > 1 ? c2 : 1);
  float* o = agg + (size_t)n * (NREL * HID) + t * 4;
  float4 r0 = {a0.x * i0, a0.y * i0, a0.z * i0, a0.w * i0};
  float4 r1 = {a1.x * i1, a1.y * i1, a1.z * i1, a1.w * i1};
  float4 r2 = {a2.x * i2, a2.y * i2, a2.z * i2, a2.w * i2};
  *(float4*)(o)           = r0;
  *(float4*)(o + HID)     = r1;
  *(float4*)(o + 2 * HID) = r2;
}

// ---------------- fused GEMM ----------------
// C[M][256] = [A1 | A2] @ [B1 ; B2] + bias, optionally + residual, ReLU, LayerNorm
// BM=64 BN=256 BK=32, 256 threads, thread tile 8 rows x (4+4) cols.
// Column tile split as [colg*4, +4) u [colg*4+128, +4): B-read lane stride 16B
// -> 4-way LDS bank conflict (1.58x) instead of 8-way (2.94x) with 8-wide tiles.
// Register-prefetch of tile k+1 before compute of tile k hides global latency.
// __launch_bounds__(256, 2): VGPR budget 256/wave. R2 post-mortem: (256,4)
// capped the budget at 128 < ~140 live regs -> acc[8][8] spilled to scratch
// (3.4 GB/dispatch write traffic, VALUBusy 13%). Do NOT raise min-waves.
#define BM 64
#define BN 256
#define BK 32

template <int EPI>  // 0 = bias only, 1 = bias + residual + relu + layernorm
__global__ __launch_bounds__(256, 2) void k_gemm(
    const float* __restrict__ A1, int lda1,
    const float* __restrict__ A2, int lda2, int K1,
    const float* __restrict__ B1, const float* __restrict__ B2,
    const float* __restrict__ bias, const float* __restrict__ res,
    const float* __restrict__ lnw, const float* __restrict__ lnb,
    float* __restrict__ C, int M, int K) {
  __shared__ float As[BK][BM];   // transposed: As[k][r]
  __shared__ float Bs[BK][BN];
  int tid = (int)threadIdx.x;
  int n0 = (int)blockIdx.x * BM;
  int rowg = tid >> 5, colg = tid & 31;
  int r0 = rowg * 8;
  int c0 = colg * 4;             // owns cols [c0,c0+4) and [c0+128,c0+132)
  float acc[8][8] = {};

  int rr = tid >> 3;             // 0..31
  int k4 = (tid & 7) << 2;       // 0,4,...,28

  float4 av[2];
  float4 bv[8];
  auto load_tile = [&](int kk) {
    const float* Ap; int ldA; int kcol;
    if (kk < K1) { Ap = A1; ldA = lda1; kcol = kk; }
    else         { Ap = A2; ldA = lda2; kcol = kk - K1; }
    #pragma unroll
    for (int hh = 0; hh < 2; ++hh) {
      int grow = n0 + rr + hh * 32;
      if (grow > M - 1) grow = M - 1;
      av[hh] = *(const float4*)(Ap + (size_t)grow * ldA + kcol + k4);
    }
    const float* Bp = (kk < K1) ? (B1 + (size_t)kk * BN) : (B2 + (size_t)(kk - K1) * BN);
    #pragma unroll
    for (int rnd = 0; rnd < 8; ++rnd) {
      int f = rnd * 256 + tid;
      bv[rnd] = *(const float4*)(Bp + (f >> 6) * BN + ((f & 63) << 2));
    }
  };

  load_tile(0);
  for (int kk = 0; kk < K; kk += BK) {
    __syncthreads();   // protect LDS from previous iteration's readers
    #pragma unroll
    for (int hh = 0; hh < 2; ++hh) {
      int r = rr + hh * 32;
      As[k4 + 0][r] = av[hh].x; As[k4 + 1][r] = av[hh].y;
      As[k4 + 2][r] = av[hh].z; As[k4 + 3][r] = av[hh].w;
    }
    #pragma unroll
    for (int rnd = 0; rnd < 8; ++rnd) {
      int f = rnd * 256 + tid;
      *(float4*)&Bs[f >> 6][(f & 63) << 2] = bv[rnd];
    }
    __syncthreads();
    if (kk + BK < K) load_tile(kk + BK);   // prefetch next tile into regs
    #pragma unroll
    for (int k = 0; k < BK; ++k) {
      float a[8], b[8];
      *(float4*)&a[0] = *(const float4*)&As[k][r0];
      *(float4*)&a[4] = *(const float4*)&As[k][r0 + 4];
      *(float4*)&b[0] = *(const float4*)&Bs[k][c0];
      *(float4*)&b[4] = *(const float4*)&Bs[k][c0 + 128];
      #pragma unroll
      for (int i = 0; i < 8; ++i)
        #pragma unroll
        for (int j = 0; j < 8; ++j)
          acc[i][j] = fmaf(a[i], b[j], acc[i][j]);
    }
  }

  // epilogue — thread's cols: j<4 -> c0+j ; j>=4 -> c0+128+(j-4)
  float bw[8];
  *(float4*)&bw[0] = *(const float4*)(bias + c0);
  *(float4*)&bw[4] = *(const float4*)(bias + c0 + 128);
  float lw[8], lB[8];
  if (EPI == 1) {
    *(float4*)&lw[0] = *(const float4*)(lnw + c0);
    *(float4*)&lw[4] = *(const float4*)(lnw + c0 + 128);
    *(float4*)&lB[0] = *(const float4*)(lnb + c0);
    *(float4*)&lB[4] = *(const float4*)(lnb + c0 + 128);
  }
  #pragma unroll
  for (int i = 0; i < 8; ++i) {
    int row = n0 + r0 + i;
    if (EPI == 0) {
      if (row < M) {
        float4 o0 = {acc[i][0] + bw[0], acc[i][1] + bw[1], acc[i][2] + bw[2], acc[i][3] + bw[3]};
        float4 o1 = {acc[i][4] + bw[4], acc[i][5] + bw[5], acc[i][6] + bw[6], acc[i][7] + bw[7]};
        *(float4*)(C + (size_t)row * BN + c0)       = o0;
        *(float4*)(C + (size_t)row * BN + c0 + 128) = o1;
      }
    } else {
      int rc = row < M ? row : M - 1;
      float4 rv0 = *(const float4*)(res + (size_t)rc * BN + c0);
      float4 rv1 = *(const float4*)(res + (size_t)rc * BN + c0 + 128);
      float v[8];
      v[0] = fmaxf(acc[i][0] + bw[0] + rv0.x, 0.f);
      v[1] = fmaxf(acc[i][1] + bw[1] + rv0.y, 0.f);
      v[2] = fmaxf(acc[i][2] + bw[2] + rv0.z, 0.f);
      v[3] = fmaxf(acc[i][3] + bw[3] + rv0.w, 0.f);
      v[4] = fmaxf(acc[i][4] + bw[4] + rv1.x, 0.f);
      v[5] = fmaxf(acc[i][5] + bw[5] + rv1.y, 0.f);
      v[6] = fmaxf(acc[i][6] + bw[6] + rv1.z, 0.f);
      v[7] = fmaxf(acc[i][7] + bw[7] + rv1.w, 0.f);
      float s = 0.f, s2 = 0.f;
      #pragma unroll
      for (int j = 0; j < 8; ++j) { s += v[j]; s2 += v[j] * v[j]; }
      #pragma unroll
      for (int mm = 1; mm < 32; mm <<= 1) {
        s  += __shfl_xor(s, mm);
        s2 += __shfl_xor(s2, mm);
      }
      float mean = s * (1.f / 256.f);
      float var = s2 * (1.f / 256.f) - mean * mean;
      float rstd = rsqrtf(var + 1e-5f);
      if (row < M) {
        float4 o0 = {(v[0] - mean) * rstd * lw[0] + lB[0], (v[1] - mean) * rstd * lw[1] + lB[1],
                     (v[2] - mean) * rstd * lw[2] + lB[2], (v[3] - mean) * rstd * lw[3] + lB[3]};
        float4 o1 = {(v[4] - mean) * rstd * lw[4] + lB[4], (v[5] - mean) * rstd * lw[5] + lB[5],
                     (v[6] - mean) * rstd * lw[6] + lB[6], (v[7] - mean) * rstd * lw[7] + lB[7]};
        *(float4*)(C + (size_t)row * BN + c0)       = o0;
        *(float4*)(C + (size_t)row * BN + c0 + 128) = o1;
      }
    }
  }
}

// ---------------- pooling + classifier ----------------
__global__ void k_pool(const float* __restrict__ h, const int* __restrict__ gstart,
                       float* __restrict__ g) {
  int gi = blockIdx.x;
  int c = blockIdx.y * 128 + threadIdx.x;
  int s = gstart[gi], e = gstart[gi + 1];
  float m = -3.402823466e+38f;
  for (int n = s; n < e; ++n) m = fmaxf(m, h[(size_t)n * HID + c]);
  g[gi * HID + c] = m;
}

__global__ __launch_bounds__(256) void k_classifier(const float* __restrict__ g,
                                                    const float* __restrict__ w1,
                                                    const float* __restrict__ b1,
                                                    const float* __restrict__ w2,
                                                    const float* __restrict__ b2,
                                                    float* __restrict__ out) {
  int gi = blockIdx.x, t = (int)threadIdx.x;
  __shared__ float gs[HID], zs[HID];
  gs[t] = g[gi * HID + t];
  __syncthreads();
  float s = b1[t];
  for (int k = 0; k < HID; ++k) s = fmaf(gs[k], w1[k * HID + t], s);
  zs[t] = fmaxf(s, 0.f);
  __syncthreads();
  if (t < 4) {
    float o = b2[t];
    for (int k = 0; k < HID; ++k) o = fmaf(zs[k], w2[k * 4 + t], o);
    out[gi * 4 + t] = o;
  }
}

// ---------------- launch ----------------
extern "C" void kernel_launch(void* const* d_in, const int* in_sizes, int n_in,
                              void* d_out, int out_size, void* d_ws, size_t ws_size,
                              hipStream_t stream) {
  const float* x      = (const float*)d_in[0];
  const int*   eidx   = (const int*)d_in[1];
  const int*   etype  = (const int*)d_in[2];
  const int*   batch  = (const int*)d_in[3];
  const float* in_w   = (const float*)d_in[4];
  const float* in_b   = (const float*)d_in[5];
  const float* root_w = (const float*)d_in[6];
  const float* rel_w  = (const float*)d_in[7];
  const float* conv_b = (const float*)d_in[8];
  const float* ln_w   = (const float*)d_in[9];
  const float* ln_b   = (const float*)d_in[10];
  const float* cls_w1 = (const float*)d_in[11];
  const float* cls_b1 = (const float*)d_in[12];
  const float* cls_w2 = (const float*)d_in[13];
  const float* cls_b2 = (const float*)d_in[14];
  float* out = (float*)d_out;

  char* ws = (char*)d_ws;
  size_t off = 0;
  auto alloc = [&](size_t bytes) -> void* {
    void* p = ws + off;
    off += (bytes + 255) & ~(size_t)255;
    return p;
  };
  float*    bufA      = (float*)alloc(sizeof(float) * (size_t)NN * HID);
  float*    bufB      = (float*)alloc(sizeof(float) * (size_t)NN * HID);
  float*    agg       = (float*)alloc(sizeof(float) * (size_t)NN * NREL * HID);
  unsigned* csr       = (unsigned*)alloc(sizeof(unsigned) * NE);
  int*      deg       = (int*)alloc(sizeof(int) * 53248);
  int*      row_start = (int*)alloc(sizeof(int) * (NN + 1));
  int*      cursor    = (int*)alloc(sizeof(int) * NN);
  int*      gstart    = (int*)alloc(sizeof(int) * (NG + 1));
  float*    gpool     = (float*)alloc(sizeof(float) * NG * HID);
  (void)ws_size; (void)in_sizes; (void)n_in; (void)out_size;

  const int* esrc = eidx;
  const int* edst = eidx + NE;

  k_zero_int<<<(53248 + 255) / 256, 256, 0, stream>>>(deg, 53248);
  k_hist<<<(NE + 255) / 256, 256, 0, stream>>>(edst, deg);
  k_scan<<<1, 1024, 0, stream>>>(deg, row_start, cursor);
  k_scatter<<<(NE + 255) / 256, 256, 0, stream>>>(esrc, edst, etype, cursor, csr);
  k_graph_bounds<<<(NN + 255) / 256, 256, 0, stream>>>(batch, gstart);

  int gemm_grid = (NN + BM - 1) / BM;
  // input projection: h = x @ in_w + in_b
  k_gemm<0><<<gemm_grid, 256, 0, stream>>>(x, IND, nullptr, 0, IND,
                                           in_w, nullptr, in_b, nullptr, nullptr, nullptr,
                                           bufA, NN, IND);

  float* hcur = bufA;
  float* hnext = bufB;
  for (int L = 0; L < NLAY; ++L) {
    k_aggregate<<<NN, 64, 0, stream>>>(hcur, row_start, csr, agg);
    k_gemm<1><<<gemm_grid, 256, 0, stream>>>(
        hcur, HID, agg, NREL * HID, HID,
        root_w + (size_t)L * HID * HID, rel_w + (size_t)L * NREL * HID * HID,
        conv_b + L * HID, hcur, ln_w + L * HID, ln_b + L * HID,
        hnext, NN, HID + NREL * HID);
    float* tmp = hcur; hcur = hnext; hnext = tmp;
  }

  k_pool<<<dim3(NG, 2), 128, 0, stream>>>(hcur, gstart, gpool);
  k_classifier<<<NG, 256, 0, stream>>>(gpool, cls_w1, cls_b1, cls_w2, cls_b2, out);
}

// Round 4
// 2308.457 us; speedup vs baseline: 2.7008x; 1.1465x over previous
//
#include <hip/hip_runtime.h>
#include <cstdint>
#include <cstddef>

#define NN 50000
#define NE 800000
#define NG 64
#define IND 768
#define HID 256
#define NREL 3
#define NLAY 3

// ---------------- utility ----------------
__global__ void k_zero_int(int* __restrict__ p, int n) {
  int i = blockIdx.x * 256 + threadIdx.x;
  if (i < n) p[i] = 0;
}

__global__ void k_hist(const int* __restrict__ dst, int* __restrict__ deg) {
  int e = blockIdx.x * 256 + threadIdx.x;
  if (e < NE) atomicAdd(&deg[dst[e]], 1);
}

// single-block scan over padded deg (53248 ints) -> row_start[NN+1], cursor[NN]
__global__ __launch_bounds__(1024) void k_scan(const int* __restrict__ deg,
                                               int* __restrict__ row_start,
                                               int* __restrict__ cursor) {
  __shared__ int wsum[16];
  int t = threadIdx.x;
  int lane = t & 63, wid = t >> 6;
  int running = 0;
  if (t == 0) row_start[0] = 0;
  for (int base = 0; base < NN; base += 4096) {
    int idx = base + t * 4;
    int4 d = *(const int4*)(deg + idx);  // deg padded+zeroed to 53248
    int s = d.x + d.y + d.z + d.w;
    int sc = s;
    #pragma unroll
    for (int off = 1; off < 64; off <<= 1) {
      int o = __shfl_up(sc, off);
      if (lane >= off) sc += o;
    }
    if (lane == 63) wsum[wid] = sc;
    __syncthreads();
    if (t == 0) {
      int a = 0;
      #pragma unroll
      for (int i = 0; i < 16; ++i) { a += wsum[i]; wsum[i] = a; }
    }
    __syncthreads();
    int woff = (wid == 0) ? 0 : wsum[wid - 1];
    int excl = running + woff + (sc - s);
    int e0 = excl, e1 = e0 + d.x, e2 = e1 + d.y, e3 = e2 + d.z, e4 = e3 + d.w;
    if (idx     < NN) { cursor[idx]     = e0; row_start[idx + 1] = e1; }
    if (idx + 1 < NN) { cursor[idx + 1] = e1; row_start[idx + 2] = e2; }
    if (idx + 2 < NN) { cursor[idx + 2] = e2; row_start[idx + 3] = e3; }
    if (idx + 3 < NN) { cursor[idx + 3] = e3; row_start[idx + 4] = e4; }
    running += wsum[15];
    __syncthreads();
  }
}

__global__ void k_scatter(const int* __restrict__ src, const int* __restrict__ dst,
                          const int* __restrict__ ety, int* __restrict__ cursor,
                          unsigned* __restrict__ csr) {
  int e = blockIdx.x * 256 + threadIdx.x;
  if (e >= NE) return;
  int pos = atomicAdd(&cursor[dst[e]], 1);
  csr[pos] = (unsigned)src[e] | ((unsigned)ety[e] << 16);  // src < 65536 fits 16 bits
}

__global__ void k_graph_bounds(const int* __restrict__ batch, int* __restrict__ gstart) {
  int i = blockIdx.x * 256 + threadIdx.x;
  if (i >= NN) return;
  int b = batch[i];
  int bp = (i == 0) ? -1 : batch[i - 1];
  for (int g = bp + 1; g <= b; ++g) gstart[g] = i;
  if (i == NN - 1) {
    for (int g = b + 1; g <= NG; ++g) gstart[g] = NN;
  }
}

// ---------------- aggregation: per-node mean per relation ----------------
// one 64-thread block per node; thread t owns channels [4t, 4t+4)
__global__ __launch_bounds__(64) void k_aggregate(const float* __restrict__ h,
                                                  const int* __restrict__ row_start,
                                                  const unsigned* __restrict__ csr,
                                                  float* __restrict__ agg) {
  int n = blockIdx.x;
  int t = threadIdx.x;
  int s = row_start[n], e = row_start[n + 1];
  float4 a0 = {0, 0, 0, 0}, a1 = {0, 0, 0, 0}, a2 = {0, 0, 0, 0};
  int c0 = 0, c1 = 0, c2 = 0;
  __shared__ unsigned buf[64];
  for (int base = s; base < e; base += 64) {
    int m = e - base; if (m > 64) m = 64;
    __syncthreads();
    if (t < m) buf[t] = csr[base + t];
    __syncthreads();
    for (int j = 0; j < m; ++j) {
      unsigned p = buf[j];
      int src = p & 0xFFFF;
      int ty = (int)(p >> 16);   // wave-uniform
      float4 v = *(const float4*)(h + (size_t)src * HID + t * 4);
      if (ty == 0)      { a0.x += v.x; a0.y += v.y; a0.z += v.z; a0.w += v.w; c0++; }
      else if (ty == 1) { a1.x += v.x; a1.y += v.y; a1.z += v.z; a1.w += v.w; c1++; }
      else              { a2.x += v.x; a2.y += v.y; a2.z += v.z; a2.w += v.w; c2++; }
    }
  }
  float i0 = 1.f / (float)(c0 > 1 ? c0 : 1);
  float i1 = 1.f / (float)(c1 > 1 ? c1 : 1);
  float i2 = 1.f / (float)(c2 > 1 ? c2 : 1);
  float* o = agg + (size_t)n * (NREL * HID) + t * 4;
  float4 r0 = {a0.x * i0, a0.y * i0, a0.z * i0, a0.w * i0};
  float4 r1 = {a1.x * i1, a1.y * i1, a1.z * i1, a1.w * i1};
  float4 r2 = {a2.x * i2, a2.y * i2, a2.z * i2, a2.w * i2};
  *(float4*)(o)           = r0;
  *(float4*)(o + HID)     = r1;
  *(float4*)(o + 2 * HID) = r2;
}

// ---------------- fused GEMM ----------------
// C[M][256] = [A1 | A2] @ [B1 ; B2] + bias, optionally + residual, ReLU, LayerNorm
// BM=64 BN=256 BK=32, 256 threads, thread tile 8 rows x (4+4) cols.
//
// R3 post-mortem: __launch_bounds__ 2nd arg empirically caps VGPRs at
// 512/(2*arg) on gfx950 hipcc ((256,4)->64, (256,2)->116+spill). Use (256,1).
// B is staged direct-to-LDS via global_load_lds (no VGPR round-trip),
// eliminating the 32-reg bv[] array; A keeps an 8-reg transposing prefetch.
// Live set ~105 VGPR -> no scratch at any cap tier >=128.
#define BM 64
#define BN 256
#define BK 32

__device__ __forceinline__ void load_lds16(const float* g, float* l) {
  __builtin_amdgcn_global_load_lds(
      (const __attribute__((address_space(1))) unsigned*)g,
      (__attribute__((address_space(3))) unsigned*)l, 16, 0, 0);
}

template <int EPI>  // 0 = bias only, 1 = bias + residual + relu + layernorm
__global__ __launch_bounds__(256, 1) void k_gemm(
    const float* __restrict__ A1, int lda1,
    const float* __restrict__ A2, int lda2, int K1,
    const float* __restrict__ B1, const float* __restrict__ B2,
    const float* __restrict__ bias, const float* __restrict__ res,
    const float* __restrict__ lnw, const float* __restrict__ lnb,
    float* __restrict__ C, int M, int K) {
  __shared__ float As[BK][BM];   // transposed: As[k][r], 8 KB
  __shared__ float Bs[BK][BN];   // 32 KB
  int tid = (int)threadIdx.x;
  int lane = tid & 63, wv = tid >> 6;
  int n0 = (int)blockIdx.x * BM;
  int rowg = tid >> 5, colg = tid & 31;
  int r0 = rowg * 8;
  int c0 = colg * 4;             // owns cols [c0,c0+4) and [c0+128,c0+132)
  float acc[8][8] = {};

  int rr = tid >> 3;             // 0..31: A-stage row within tile
  int k4 = (tid & 7) << 2;       // 0,4,...,28: A-stage k offset

  // clamped global rows for the A prefetch (bounds-safe, uniform per thread)
  int grow0 = n0 + rr;       if (grow0 > M - 1) grow0 = M - 1;
  int grow1 = n0 + rr + 32;  if (grow1 > M - 1) grow1 = M - 1;

  float4 av0, av1;
  {  // prefetch A tile 0
    const float* Ap = (0 < K1) ? A1 : A2;
    int ld = (0 < K1) ? lda1 : lda2;
    av0 = *(const float4*)(Ap + (size_t)grow0 * ld + k4);
    av1 = *(const float4*)(Ap + (size_t)grow1 * ld + k4);
  }

  for (int kk = 0; kk < K; kk += BK) {
    __syncthreads();   // previous tile's LDS reads complete
    // store A tile (registers -> transposed LDS)
    As[k4 + 0][rr] = av0.x; As[k4 + 1][rr] = av0.y;
    As[k4 + 2][rr] = av0.z; As[k4 + 3][rr] = av0.w;
    As[k4 + 0][rr + 32] = av1.x; As[k4 + 1][rr + 32] = av1.y;
    As[k4 + 2][rr + 32] = av1.z; As[k4 + 3][rr + 32] = av1.w;
    // issue B tile: global -> LDS direct, one 1KB row per wave-issue
    {
      const float* Bp = (kk < K1) ? (B1 + (size_t)kk * BN)
                                  : (B2 + (size_t)(kk - K1) * BN);
      #pragma unroll
      for (int i = 0; i < 8; ++i) {
        int row = wv * 8 + i;
        load_lds16(Bp + (size_t)row * BN + lane * 4, &Bs[row][0]);
      }
    }
    __syncthreads();   // vmcnt+lgkm drain: As and Bs resident
    // prefetch next A tile into registers (hidden under compute)
    int kn = kk + BK;
    if (kn < K) {
      const float* Ap; int ld; int kcol;
      if (kn < K1) { Ap = A1; ld = lda1; kcol = kn; }
      else         { Ap = A2; ld = lda2; kcol = kn - K1; }
      av0 = *(const float4*)(Ap + (size_t)grow0 * ld + kcol + k4);
      av1 = *(const float4*)(Ap + (size_t)grow1 * ld + kcol + k4);
    }
    #pragma unroll
    for (int k = 0; k < BK; ++k) {
      float a[8], b[8];
      *(float4*)&a[0] = *(const float4*)&As[k][r0];
      *(float4*)&a[4] = *(const float4*)&As[k][r0 + 4];
      *(float4*)&b[0] = *(const float4*)&Bs[k][c0];
      *(float4*)&b[4] = *(const float4*)&Bs[k][c0 + 128];
      #pragma unroll
      for (int i = 0; i < 8; ++i)
        #pragma unroll
        for (int j = 0; j < 8; ++j)
          acc[i][j] = fmaf(a[i], b[j], acc[i][j]);
    }
  }

  // epilogue — thread's cols: j<4 -> c0+j ; j>=4 -> c0+128+(j-4)
  float bw[8];
  *(float4*)&bw[0] = *(const float4*)(bias + c0);
  *(float4*)&bw[4] = *(const float4*)(bias + c0 + 128);
  float lw[8], lB[8];
  if (EPI == 1) {
    *(float4*)&lw[0] = *(const float4*)(lnw + c0);
    *(float4*)&lw[4] = *(const float4*)(lnw + c0 + 128);
    *(float4*)&lB[0] = *(const float4*)(lnb + c0);
    *(float4*)&lB[4] = *(const float4*)(lnb + c0 + 128);
  }
  #pragma unroll
  for (int i = 0; i < 8; ++i) {
    int row = n0 + r0 + i;
    if (EPI == 0) {
      if (row < M) {
        float4 o0 = {acc[i][0] + bw[0], acc[i][1] + bw[1], acc[i][2] + bw[2], acc[i][3] + bw[3]};
        float4 o1 = {acc[i][4] + bw[4], acc[i][5] + bw[5], acc[i][6] + bw[6], acc[i][7] + bw[7]};
        *(float4*)(C + (size_t)row * BN + c0)       = o0;
        *(float4*)(C + (size_t)row * BN + c0 + 128) = o1;
      }
    } else {
      int rc = row < M ? row : M - 1;
      float4 rv0 = *(const float4*)(res + (size_t)rc * BN + c0);
      float4 rv1 = *(const float4*)(res + (size_t)rc * BN + c0 + 128);
      float v[8];
      v[0] = fmaxf(acc[i][0] + bw[0] + rv0.x, 0.f);
      v[1] = fmaxf(acc[i][1] + bw[1] + rv0.y, 0.f);
      v[2] = fmaxf(acc[i][2] + bw[2] + rv0.z, 0.f);
      v[3] = fmaxf(acc[i][3] + bw[3] + rv0.w, 0.f);
      v[4] = fmaxf(acc[i][4] + bw[4] + rv1.x, 0.f);
      v[5] = fmaxf(acc[i][5] + bw[5] + rv1.y, 0.f);
      v[6] = fmaxf(acc[i][6] + bw[6] + rv1.z, 0.f);
      v[7] = fmaxf(acc[i][7] + bw[7] + rv1.w, 0.f);
      float s = 0.f, s2 = 0.f;
      #pragma unroll
      for (int j = 0; j < 8; ++j) { s += v[j]; s2 += v[j] * v[j]; }
      #pragma unroll
      for (int mm = 1; mm < 32; mm <<= 1) {
        s  += __shfl_xor(s, mm);
        s2 += __shfl_xor(s2, mm);
      }
      float mean = s * (1.f / 256.f);
      float var = s2 * (1.f / 256.f) - mean * mean;
      float rstd = rsqrtf(var + 1e-5f);
      if (row < M) {
        float4 o0 = {(v[0] - mean) * rstd * lw[0] + lB[0], (v[1] - mean) * rstd * lw[1] + lB[1],
                     (v[2] - mean) * rstd * lw[2] + lB[2], (v[3] - mean) * rstd * lw[3] + lB[3]};
        float4 o1 = {(v[4] - mean) * rstd * lw[4] + lB[4], (v[5] - mean) * rstd * lw[5] + lB[5],
                     (v[6] - mean) * rstd * lw[6] + lB[6], (v[7] - mean) * rstd * lw[7] + lB[7]};
        *(float4*)(C + (size_t)row * BN + c0)       = o0;
        *(float4*)(C + (size_t)row * BN + c0 + 128) = o1;
      }
    }
  }
}

// ---------------- pooling + classifier ----------------
__global__ void k_pool(const float* __restrict__ h, const int* __restrict__ gstart,
                       float* __restrict__ g) {
  int gi = blockIdx.x;
  int c = blockIdx.y * 128 + threadIdx.x;
  int s = gstart[gi], e = gstart[gi + 1];
  float m = -3.402823466e+38f;
  for (int n = s; n < e; ++n) m = fmaxf(m, h[(size_t)n * HID + c]);
  g[gi * HID + c] = m;
}

__global__ __launch_bounds__(256) void k_classifier(const float* __restrict__ g,
                                                    const float* __restrict__ w1,
                                                    const float* __restrict__ b1,
                                                    const float* __restrict__ w2,
                                                    const float* __restrict__ b2,
                                                    float* __restrict__ out) {
  int gi = blockIdx.x, t = (int)threadIdx.x;
  __shared__ float gs[HID], zs[HID];
  gs[t] = g[gi * HID + t];
  __syncthreads();
  float s = b1[t];
  for (int k = 0; k < HID; ++k) s = fmaf(gs[k], w1[k * HID + t], s);
  zs[t] = fmaxf(s, 0.f);
  __syncthreads();
  if (t < 4) {
    float o = b2[t];
    for (int k = 0; k < HID; ++k) o = fmaf(zs[k], w2[k * 4 + t], o);
    out[gi * 4 + t] = o;
  }
}

// ---------------- launch ----------------
extern "C" void kernel_launch(void* const* d_in, const int* in_sizes, int n_in,
                              void* d_out, int out_size, void* d_ws, size_t ws_size,
                              hipStream_t stream) {
  const float* x      = (const float*)d_in[0];
  const int*   eidx   = (const int*)d_in[1];
  const int*   etype  = (const int*)d_in[2];
  const int*   batch  = (const int*)d_in[3];
  const float* in_w   = (const float*)d_in[4];
  const float* in_b   = (const float*)d_in[5];
  const float* root_w = (const float*)d_in[6];
  const float* rel_w  = (const float*)d_in[7];
  const float* conv_b = (const float*)d_in[8];
  const float* ln_w   = (const float*)d_in[9];
  const float* ln_b   = (const float*)d_in[10];
  const float* cls_w1 = (const float*)d_in[11];
  const float* cls_b1 = (const float*)d_in[12];
  const float* cls_w2 = (const float*)d_in[13];
  const float* cls_b2 = (const float*)d_in[14];
  float* out = (float*)d_out;

  char* ws = (char*)d_ws;
  size_t off = 0;
  auto alloc = [&](size_t bytes) -> void* {
    void* p = ws + off;
    off += (bytes + 255) & ~(size_t)255;
    return p;
  };
  float*    bufA      = (float*)alloc(sizeof(float) * (size_t)NN * HID);
  float*    bufB      = (float*)alloc(sizeof(float) * (size_t)NN * HID);
  float*    agg       = (float*)alloc(sizeof(float) * (size_t)NN * NREL * HID);
  unsigned* csr       = (unsigned*)alloc(sizeof(unsigned) * NE);
  int*      deg       = (int*)alloc(sizeof(int) * 53248);
  int*      row_start = (int*)alloc(sizeof(int) * (NN + 1));
  int*      cursor    = (int*)alloc(sizeof(int) * NN);
  int*      gstart    = (int*)alloc(sizeof(int) * (NG + 1));
  float*    gpool     = (float*)alloc(sizeof(float) * NG * HID);
  (void)ws_size; (void)in_sizes; (void)n_in; (void)out_size;

  const int* esrc = eidx;
  const int* edst = eidx + NE;

  k_zero_int<<<(53248 + 255) / 256, 256, 0, stream>>>(deg, 53248);
  k_hist<<<(NE + 255) / 256, 256, 0, stream>>>(edst, deg);
  k_scan<<<1, 1024, 0, stream>>>(deg, row_start, cursor);
  k_scatter<<<(NE + 255) / 256, 256, 0, stream>>>(esrc, edst, etype, cursor, csr);
  k_graph_bounds<<<(NN + 255) / 256, 256, 0, stream>>>(batch, gstart);

  int gemm_grid = (NN + BM - 1) / BM;
  // input projection: h = x @ in_w + in_b
  k_gemm<0><<<gemm_grid, 256, 0, stream>>>(x, IND, nullptr, 0, IND,
                                           in_w, nullptr, in_b, nullptr, nullptr, nullptr,
                                           bufA, NN, IND);

  float* hcur = bufA;
  float* hnext = bufB;
  for (int L = 0; L < NLAY; ++L) {
    k_aggregate<<<NN, 64, 0, stream>>>(hcur, row_start, csr, agg);
    k_gemm<1><<<gemm_grid, 256, 0, stream>>>(
        hcur, HID, agg, NREL * HID, HID,
        root_w + (size_t)L * HID * HID, rel_w + (size_t)L * NREL * HID * HID,
        conv_b + L * HID, hcur, ln_w + L * HID, ln_b + L * HID,
        hnext, NN, HID + NREL * HID);
    float* tmp = hcur; hcur = hnext; hnext = tmp;
  }

  k_pool<<<dim3(NG, 2), 128, 0, stream>>>(hcur, gstart, gpool);
  k_classifier<<<NG, 256, 0, stream>>>(gpool, cls_w1, cls_b1, cls_w2, cls_b2, out);
}

// Round 6
// 1336.982 us; speedup vs baseline: 4.6633x; 1.7266x over previous
//
#include <hip/hip_runtime.h>
#include <cstdint>
#include <cstddef>

#define NN 50000
#define NE 800000
#define NG 64
#define IND 768
#define HID 256
#define NREL 3
#define NLAY 3

typedef __attribute__((ext_vector_type(4))) float f32x4;
typedef __attribute__((ext_vector_type(8))) short s16x8;

// ---------------- utility ----------------
__global__ void k_zero_int(int* __restrict__ p, int n) {
  int i = blockIdx.x * 256 + threadIdx.x;
  if (i < n) p[i] = 0;
}

__global__ void k_hist(const int* __restrict__ dst, int* __restrict__ deg) {
  int e = blockIdx.x * 256 + threadIdx.x;
  if (e < NE) atomicAdd(&deg[dst[e]], 1);
}

__global__ __launch_bounds__(1024) void k_scan(const int* __restrict__ deg,
                                               int* __restrict__ row_start,
                                               int* __restrict__ cursor) {
  __shared__ int wsum[16];
  int t = threadIdx.x;
  int lane = t & 63, wid = t >> 6;
  int running = 0;
  if (t == 0) row_start[0] = 0;
  for (int base = 0; base < NN; base += 4096) {
    int idx = base + t * 4;
    int4 d = *(const int4*)(deg + idx);
    int s = d.x + d.y + d.z + d.w;
    int sc = s;
    #pragma unroll
    for (int off = 1; off < 64; off <<= 1) {
      int o = __shfl_up(sc, off);
      if (lane >= off) sc += o;
    }
    if (lane == 63) wsum[wid] = sc;
    __syncthreads();
    if (t == 0) {
      int a = 0;
      #pragma unroll
      for (int i = 0; i < 16; ++i) { a += wsum[i]; wsum[i] = a; }
    }
    __syncthreads();
    int woff = (wid == 0) ? 0 : wsum[wid - 1];
    int excl = running + woff + (sc - s);
    int e0 = excl, e1 = e0 + d.x, e2 = e1 + d.y, e3 = e2 + d.z, e4 = e3 + d.w;
    if (idx     < NN) { cursor[idx]     = e0; row_start[idx + 1] = e1; }
    if (idx + 1 < NN) { cursor[idx + 1] = e1; row_start[idx + 2] = e2; }
    if (idx + 2 < NN) { cursor[idx + 2] = e2; row_start[idx + 3] = e3; }
    if (idx + 3 < NN) { cursor[idx + 3] = e3; row_start[idx + 4] = e4; }
    running += wsum[15];
    __syncthreads();
  }
}

__global__ void k_scatter(const int* __restrict__ src, const int* __restrict__ dst,
                          const int* __restrict__ ety, int* __restrict__ cursor,
                          unsigned* __restrict__ csr) {
  int e = blockIdx.x * 256 + threadIdx.x;
  if (e >= NE) return;
  int pos = atomicAdd(&cursor[dst[e]], 1);
  csr[pos] = (unsigned)src[e] | ((unsigned)ety[e] << 16);
}

__global__ void k_graph_bounds(const int* __restrict__ batch, int* __restrict__ gstart) {
  int i = blockIdx.x * 256 + threadIdx.x;
  if (i >= NN) return;
  int b = batch[i];
  int bp = (i == 0) ? -1 : batch[i - 1];
  for (int g = bp + 1; g <= b; ++g) gstart[g] = i;
  if (i == NN - 1) {
    for (int g = b + 1; g <= NG; ++g) gstart[g] = NN;
  }
}

// ---------------- aggregation ----------------
__global__ __launch_bounds__(64) void k_aggregate(const float* __restrict__ h,
                                                  const int* __restrict__ row_start,
                                                  const unsigned* __restrict__ csr,
                                                  float* __restrict__ agg) {
  int n = blockIdx.x;
  int t = threadIdx.x;
  int s = row_start[n], e = row_start[n + 1];
  float4 a0 = {0, 0, 0, 0}, a1 = {0, 0, 0, 0}, a2 = {0, 0, 0, 0};
  int c0 = 0, c1 = 0, c2 = 0;
  __shared__ unsigned buf[64];
  for (int base = s; base < e; base += 64) {
    int m = e - base; if (m > 64) m = 64;
    __syncthreads();
    if (t < m) buf[t] = csr[base + t];
    __syncthreads();
    for (int j = 0; j < m; ++j) {
      unsigned p = buf[j];
      int src = p & 0xFFFF;
      int ty = (int)(p >> 16);
      float4 v = *(const float4*)(h + (size_t)src * HID + t * 4);
      if (ty == 0)      { a0.x += v.x; a0.y += v.y; a0.z += v.z; a0.w += v.w; c0++; }
      else if (ty == 1) { a1.x += v.x; a1.y += v.y; a1.z += v.z; a1.w += v.w; c1++; }
      else              { a2.x += v.x; a2.y += v.y; a2.z += v.z; a2.w += v.w; c2++; }
    }
  }
  float i0 = 1.f / (float)(c0 > 1 ? c0 : 1);
  float i1 = 1.f / (float)(c1 > 1 ? c1 : 1);
  float i2 = 1.f / (float)(c2 > 1 ? c2 : 1);
  float* o = agg + (size_t)n * (NREL * HID) + t * 4;
  float4 r0 = {a0.x * i0, a0.y * i0, a0.z * i0, a0.w * i0};
  float4 r1 = {a1.x * i1, a1.y * i1, a1.z * i1, a1.w * i1};
  float4 r2 = {a2.x * i2, a2.y * i2, a2.z * i2, a2.w * i2};
  *(float4*)(o)           = r0;
  *(float4*)(o + HID)     = r1;
  *(float4*)(o + 2 * HID) = r2;
}

// ---------------- bf16 split helpers ----------------
__device__ __forceinline__ unsigned short bf16rne(float f) {
  union { float f; unsigned u; } x; x.f = f;
  unsigned r = (x.u + 0x7FFFu + ((x.u >> 16) & 1u)) >> 16;
  return (unsigned short)r;
}
__device__ __forceinline__ float bf2f(unsigned short h) {
  union { unsigned u; float f; } x; x.u = ((unsigned)h) << 16;
  return x.f;
}

// weight convert: fp32 [Ktot][256] (two contiguous pieces) ->
// hi/lo bf16 packed [Ktot/8][256][8]  (linear for global_load_lds staging)
__global__ void k_cvt(const float* __restrict__ s1, int K1e,
                      const float* __restrict__ s2, int Ktot,
                      unsigned short* __restrict__ hi, unsigned short* __restrict__ lo) {
  int t = blockIdx.x * 256 + threadIdx.x;
  if (t >= Ktot * 256) return;
  int c = t & 255, k = t >> 8;
  float v = (k < K1e) ? s1[(size_t)k * 256 + c] : s2[(size_t)(k - K1e) * 256 + c];
  unsigned short h = bf16rne(v);
  unsigned short l = bf16rne(v - bf2f(h));
  size_t o = ((size_t)(k >> 3) * 256 + c) * 8 + (k & 7);
  hi[o] = h; lo[o] = l;
}

__device__ __forceinline__ void load_lds16b(const void* g, void* l) {
  __builtin_amdgcn_global_load_lds(
      (const __attribute__((address_space(1))) unsigned*)g,
      (__attribute__((address_space(3))) unsigned*)l, 16, 0, 0);
}

// ---------------- MFMA GEMM (fp32 via 3-term bf16 split) ----------------
// C[M][256] = [A1|A2] @ B + bias (+res, relu, LN).  Block: 256 thr = 4 waves,
// tile 64 rows x 256 cols; wave tile 64x64 = 4x4 frags of 16x16; BK=32.
// LDS layouts [kgroup][row][8bf16] make staging writes and frag reads
// conflict-free (bank-floor).  B pre-split to hi/lo packed [K/8][256][8].
// acc += Ahi*Bhi + Ahi*Blo + Alo*Bhi  (fp32 MFMA accumulate, ~16-bit mantissa).
template <int EPI>
__global__ __launch_bounds__(256, 1) void k_gemm_mfma(
    const float* __restrict__ A1, int lda1,
    const float* __restrict__ A2, int lda2, int K1,
    const unsigned short* __restrict__ Bhi, const unsigned short* __restrict__ Blo,
    const float* __restrict__ bias, const float* __restrict__ res,
    const float* __restrict__ lnw, const float* __restrict__ lnb,
    float* __restrict__ C, int M, int K) {
  __shared__ __align__(16) unsigned short AsH[4 * 64 * 8], AsL[4 * 64 * 8];   // 4KB each
  __shared__ __align__(16) unsigned short BsH[4 * 256 * 8], BsL[4 * 256 * 8]; // 16KB each
  __shared__ float lnred[64 * 4 * 2];                                         // 2KB
  int tid = (int)threadIdx.x;
  int lane = tid & 63, wv = tid >> 6;
  int n0 = (int)blockIdx.x * 64;
  // staging (A): thread covers row=tid>>2 (0..63), k-chunk sg=tid&3 (8 k each)
  int srow = tid >> 2, sg = tid & 3;
  int grow = n0 + srow; if (grow > M - 1) grow = M - 1;
  // compute: frag indices
  int c16 = lane & 15, kg = lane >> 4;
  int col0 = wv * 64;

  f32x4 acc[4][4] = {};

  for (int kt = 0; kt < K / 32; ++kt) {
    int kk = kt * 32;
    const float* Ap; int ld, kc;
    if (kk < K1) { Ap = A1; ld = lda1; kc = kk; }
    else         { Ap = A2; ld = lda2; kc = kk - K1; }
    const float* ap = Ap + (size_t)grow * ld + kc + sg * 8;
    float4 a0 = *(const float4*)ap;
    float4 a1 = *(const float4*)(ap + 4);
    __syncthreads();   // prior tile's frag reads complete
    // B: global->LDS DMA, 8 issues/wave, 1KB each, linear
    #pragma unroll
    for (int i = 0; i < 8; ++i) {
      int id = wv * 8 + i;
      const unsigned short* src = (id < 16) ? Bhi : Blo;
      unsigned short* dst = (id < 16) ? BsH : BsL;
      int rem = id & 15, g = rem >> 2, ch = rem & 3;
      load_lds16b(src + (size_t)(kt * 4 + g) * 2048 + (ch * 64 + lane) * 8,
                  dst + (g * 256 + ch * 64) * 8);
    }
    // A: split to bf16 hi/lo, write 16B each
    float va[8] = {a0.x, a0.y, a0.z, a0.w, a1.x, a1.y, a1.z, a1.w};
    s16x8 hv, lv;
    #pragma unroll
    for (int j = 0; j < 8; ++j) {
      unsigned short h = bf16rne(va[j]);
      hv[j] = (short)h;
      lv[j] = (short)bf16rne(va[j] - bf2f(h));
    }
    *(s16x8*)&AsH[(sg * 64 + srow) * 8] = hv;
    *(s16x8*)&AsL[(sg * 64 + srow) * 8] = lv;
    __syncthreads();   // drains vmcnt (B DMA) + lgkm (A writes)
    // fragments + MFMA
    s16x8 ah[4], al[4];
    #pragma unroll
    for (int ri = 0; ri < 4; ++ri) {
      int ao = (kg * 64 + ri * 16 + c16) * 8;
      ah[ri] = *(const s16x8*)&AsH[ao];
      al[ri] = *(const s16x8*)&AsL[ao];
    }
    #pragma unroll
    for (int ci = 0; ci < 4; ++ci) {
      int bo = (kg * 256 + col0 + ci * 16 + c16) * 8;
      s16x8 bh = *(const s16x8*)&BsH[bo];
      s16x8 bl = *(const s16x8*)&BsL[bo];
      #pragma unroll
      for (int ri = 0; ri < 4; ++ri) {
        acc[ri][ci] = __builtin_amdgcn_mfma_f32_16x16x32_bf16(ah[ri], bh, acc[ri][ci], 0, 0, 0);
        acc[ri][ci] = __builtin_amdgcn_mfma_f32_16x16x32_bf16(ah[ri], bl, acc[ri][ci], 0, 0, 0);
        acc[ri][ci] = __builtin_amdgcn_mfma_f32_16x16x32_bf16(al[ri], bh, acc[ri][ci], 0, 0, 0);
      }
    }
  }

  // ---------------- epilogue ----------------
  // C/D layout (verified m89/m91): col = lane&15, row = (lane>>4)*4 + reg
  float bw[4], lw[4], lb[4];
  #pragma unroll
  for (int ci = 0; ci < 4; ++ci) {
    int col = col0 + ci * 16 + c16;
    bw[ci] = bias[col];
    if (EPI == 1) { lw[ci] = lnw[col]; lb[ci] = lnb[col]; }
  }
  if (EPI == 0) {
    #pragma unroll
    for (int ri = 0; ri < 4; ++ri)
      #pragma unroll
      for (int q = 0; q < 4; ++q) {
        int row = n0 + ri * 16 + kg * 4 + q;
        if (row < M) {
          #pragma unroll
          for (int ci = 0; ci < 4; ++ci)
            C[(size_t)row * 256 + col0 + ci * 16 + c16] = acc[ri][ci][q] + bw[ci];
        }
      }
  } else {
    // v = relu(acc + bias + res); LN over 256 cols (4 col-waves via LDS)
    #pragma unroll
    for (int ri = 0; ri < 4; ++ri)
      #pragma unroll
      for (int q = 0; q < 4; ++q) {
        int rl = ri * 16 + kg * 4 + q;
        int rr = n0 + rl; int rc = rr < M ? rr : M - 1;
        float s = 0.f, s2 = 0.f;
        #pragma unroll
        for (int ci = 0; ci < 4; ++ci) {
          float r = res[(size_t)rc * 256 + col0 + ci * 16 + c16];
          float v = fmaxf(acc[ri][ci][q] + bw[ci] + r, 0.f);
          acc[ri][ci][q] = v;
          s += v; s2 += v * v;
        }
        #pragma unroll
        for (int m = 1; m < 16; m <<= 1) {
          s  += __shfl_xor(s, m);
          s2 += __shfl_xor(s2, m);
        }
        if (c16 == 0) {
          lnred[(rl * 4 + wv) * 2]     = s;
          lnred[(rl * 4 + wv) * 2 + 1] = s2;
        }
      }
    __syncthreads();
    #pragma unroll
    for (int ri = 0; ri < 4; ++ri)
      #pragma unroll
      for (int q = 0; q < 4; ++q) {
        int rl = ri * 16 + kg * 4 + q;
        float S = 0.f, S2 = 0.f;
        #pragma unroll
        for (int w = 0; w < 4; ++w) {
          S  += lnred[(rl * 4 + w) * 2];
          S2 += lnred[(rl * 4 + w) * 2 + 1];
        }
        float mean = S * (1.f / 256.f);
        float var = S2 * (1.f / 256.f) - mean * mean;
        float rstd = rsqrtf(var + 1e-5f);
        int row = n0 + rl;
        if (row < M) {
          #pragma unroll
          for (int ci = 0; ci < 4; ++ci)
            C[(size_t)row * 256 + col0 + ci * 16 + c16] =
                (acc[ri][ci][q] - mean) * rstd * lw[ci] + lb[ci];
        }
      }
  }
}

// ---------------- pooling + classifier ----------------
__global__ void k_pool(const float* __restrict__ h, const int* __restrict__ gstart,
                       float* __restrict__ g) {
  int gi = blockIdx.x;
  int c = blockIdx.y * 128 + threadIdx.x;
  int s = gstart[gi], e = gstart[gi + 1];
  float m = -3.402823466e+38f;
  for (int n = s; n < e; ++n) m = fmaxf(m, h[(size_t)n * HID + c]);
  g[gi * HID + c] = m;
}

__global__ __launch_bounds__(256) void k_classifier(const float* __restrict__ g,
                                                    const float* __restrict__ w1,
                                                    const float* __restrict__ b1,
                                                    const float* __restrict__ w2,
                                                    const float* __restrict__ b2,
                                                    float* __restrict__ out) {
  int gi = blockIdx.x, t = (int)threadIdx.x;
  __shared__ float gs[HID], zs[HID];
  gs[t] = g[gi * HID + t];
  __syncthreads();
  float s = b1[t];
  for (int k = 0; k < HID; ++k) s = fmaf(gs[k], w1[k * HID + t], s);
  zs[t] = fmaxf(s, 0.f);
  __syncthreads();
  if (t < 4) {
    float o = b2[t];
    for (int k = 0; k < HID; ++k) o = fmaf(zs[k], w2[k * 4 + t], o);
    out[gi * 4 + t] = o;
  }
}

// ---------------- launch ----------------
extern "C" void kernel_launch(void* const* d_in, const int* in_sizes, int n_in,
                              void* d_out, int out_size, void* d_ws, size_t ws_size,
                              hipStream_t stream) {
  const float* x      = (const float*)d_in[0];
  const int*   eidx   = (const int*)d_in[1];
  const int*   etype  = (const int*)d_in[2];
  const int*   batch  = (const int*)d_in[3];
  const float* in_w   = (const float*)d_in[4];
  const float* in_b   = (const float*)d_in[5];
  const float* root_w = (const float*)d_in[6];
  const float* rel_w  = (const float*)d_in[7];
  const float* conv_b = (const float*)d_in[8];
  const float* ln_w   = (const float*)d_in[9];
  const float* ln_b   = (const float*)d_in[10];
  const float* cls_w1 = (const float*)d_in[11];
  const float* cls_b1 = (const float*)d_in[12];
  const float* cls_w2 = (const float*)d_in[13];
  const float* cls_b2 = (const float*)d_in[14];
  float* out = (float*)d_out;

  char* ws = (char*)d_ws;
  size_t off = 0;
  auto alloc = [&](size_t bytes) -> void* {
    void* p = ws + off;
    off += (bytes + 255) & ~(size_t)255;
    return p;
  };
  float*    bufA      = (float*)alloc(sizeof(float) * (size_t)NN * HID);
  float*    bufB      = (float*)alloc(sizeof(float) * (size_t)NN * HID);
  float*    agg       = (float*)alloc(sizeof(float) * (size_t)NN * NREL * HID);
  unsigned* csr       = (unsigned*)alloc(sizeof(unsigned) * NE);
  int*      deg       = (int*)alloc(sizeof(int) * 53248);
  int*      row_start = (int*)alloc(sizeof(int) * (NN + 1));
  int*      cursor    = (int*)alloc(sizeof(int) * NN);
  int*      gstart    = (int*)alloc(sizeof(int) * (NG + 1));
  float*    gpool     = (float*)alloc(sizeof(float) * NG * HID);
  // packed bf16 hi/lo weights: [K/8][256][8]
  unsigned short* wInH = (unsigned short*)alloc(sizeof(unsigned short) * 96 * 256 * 8);
  unsigned short* wInL = (unsigned short*)alloc(sizeof(unsigned short) * 96 * 256 * 8);
  unsigned short* wLH[NLAY];
  unsigned short* wLL[NLAY];
  for (int L = 0; L < NLAY; ++L) {
    wLH[L] = (unsigned short*)alloc(sizeof(unsigned short) * 128 * 256 * 8);
    wLL[L] = (unsigned short*)alloc(sizeof(unsigned short) * 128 * 256 * 8);
  }
  (void)ws_size; (void)in_sizes; (void)n_in; (void)out_size;

  const int* esrc = eidx;
  const int* edst = eidx + NE;

  // weight conversion (independent of graph build)
  k_cvt<<<IND, 256, 0, stream>>>(in_w, IND, nullptr, IND, wInH, wInL);
  for (int L = 0; L < NLAY; ++L)
    k_cvt<<<HID + NREL * HID, 256, 0, stream>>>(
        root_w + (size_t)L * HID * HID, HID,
        rel_w + (size_t)L * NREL * HID * HID, HID + NREL * HID, wLH[L], wLL[L]);

  k_zero_int<<<(53248 + 255) / 256, 256, 0, stream>>>(deg, 53248);
  k_hist<<<(NE + 255) / 256, 256, 0, stream>>>(edst, deg);
  k_scan<<<1, 1024, 0, stream>>>(deg, row_start, cursor);
  k_scatter<<<(NE + 255) / 256, 256, 0, stream>>>(esrc, edst, etype, cursor, csr);
  k_graph_bounds<<<(NN + 255) / 256, 256, 0, stream>>>(batch, gstart);

  int gemm_grid = (NN + 63) / 64;   // 782
  // input projection: h = x @ in_w + in_b
  k_gemm_mfma<0><<<gemm_grid, 256, 0, stream>>>(
      x, IND, nullptr, 0, IND, wInH, wInL, in_b,
      nullptr, nullptr, nullptr, bufA, NN, IND);

  float* hcur = bufA;
  float* hnext = bufB;
  for (int L = 0; L < NLAY; ++L) {
    k_aggregate<<<NN, 64, 0, stream>>>(hcur, row_start, csr, agg);
    k_gemm_mfma<1><<<gemm_grid, 256, 0, stream>>>(
        hcur, HID, agg, NREL * HID, HID, wLH[L], wLL[L],
        conv_b + L * HID, hcur, ln_w + L * HID, ln_b + L * HID,
        hnext, NN, HID + NREL * HID);
    float* tmp = hcur; hcur = hnext; hnext = tmp;
  }

  k_pool<<<dim3(NG, 2), 128, 0, stream>>>(hcur, gstart, gpool);
  k_classifier<<<NG, 256, 0, stream>>>(gpool, cls_w1, cls_b1, cls_w2, cls_b2, out);
}